// Round 4
// baseline (2097.004 us; speedup 1.0000x reference)
//
#include <hip/hip_runtime.h>
#include <math.h>

typedef unsigned short bfu;

// ---------- dtype-dual scalar load/store ----------
__device__ __forceinline__ float b2f(bfu v) { return __uint_as_float((unsigned)v << 16); }
__device__ __forceinline__ bfu f2b(float f) {
    unsigned u = __float_as_uint(f);
    u += 0x7fffu + ((u >> 16) & 1u);   // RNE
    return (bfu)(u >> 16);
}
template<bool F32> __device__ __forceinline__ float ldg(const void* p, size_t i) {
    if (F32) return ((const float*)p)[i];
    else     return b2f(((const bfu*)p)[i]);
}
template<bool F32> __device__ __forceinline__ void stg(void* p, size_t i, float v) {
    if (F32) ((float*)p)[i] = v;
    else     ((bfu*)p)[i] = f2b(v);
}

// Problem constants
#define CC    192
#define C3    576
#define CM    768
#define MROWS 131072   // 8*128*128
#define SHIFT 4

// ---------------- dtype probe ----------------
// View first 4096 elements of x as bf16. True bf16 N(0,1) data: all |v|<6.
// fp32 data viewed as bf16: even elements are float mantissa bits -> huge/NaN.
__global__ void detect_kernel(const void* x, int* flag) {
    __shared__ int bad;
    if (threadIdx.x == 0) bad = 0;
    __syncthreads();
    int local = 0;
    for (int i = 0; i < 16; i++) {
        float v = b2f(((const bfu*)x)[threadIdx.x + i * 256]);
        if (!(fabsf(v) < 1000.0f)) local = 1;   // NaN also fails the compare
    }
    if (local) atomicOr(&bad, 1);
    __syncthreads();
    if (threadIdx.x == 0) *flag = bad;          // 1 -> fp32, 0 -> bf16
}

// ---------------- LayerNorm ----------------
// REMAP: read x at shifted/window-gathered global rows; else read global row rg.
// Output is chunk-local canonical fp32.
template<bool REMAP, bool F32>
__device__ void ln_body(const void* x, const void* sc, const void* bi,
                        float* o, int row0)
{
    const int rg = row0 + blockIdx.x;
    size_t src;
    if (REMAP) {
        int w = rg >> 6, n = rg & 63;
        int b = w >> 8, wi = (w >> 4) & 15, wj = w & 15;
        int ii = wi * 8 + (n >> 3), jj = wj * 8 + (n & 7);
        int si = (ii + SHIFT) & 127, sj = (jj + SHIFT) & 127;
        src = (((size_t)b << 14) + ((size_t)si << 7) + sj) * CC;
    } else {
        src = (size_t)rg * CC;
    }
    const int t = threadIdx.x;
    float v0 = ldg<F32>(x, src + t);
    float v1 = ldg<F32>(x, src + t + 64);
    float v2 = ldg<F32>(x, src + t + 128);
    float sum = v0 + v1 + v2;
    float sq  = v0 * v0 + v1 * v1 + v2 * v2;
    #pragma unroll
    for (int off = 32; off > 0; off >>= 1) {
        sum += __shfl_xor(sum, off);
        sq  += __shfl_xor(sq, off);
    }
    float mu  = sum * (1.0f / 192.0f);
    float var = sq * (1.0f / 192.0f) - mu * mu;
    float rs  = rsqrtf(var + 1e-5f);
    size_t dst = (size_t)blockIdx.x * CC;
    o[dst + t]       = (v0 - mu) * rs * ldg<F32>(sc, t)       + ldg<F32>(bi, t);
    o[dst + t + 64]  = (v1 - mu) * rs * ldg<F32>(sc, t + 64)  + ldg<F32>(bi, t + 64);
    o[dst + t + 128] = (v2 - mu) * rs * ldg<F32>(sc, t + 128) + ldg<F32>(bi, t + 128);
}

template<bool REMAP>
__global__ __launch_bounds__(64) void ln_kernel(
    const int* __restrict__ flag, const void* __restrict__ x,
    const void* __restrict__ sc, const void* __restrict__ bi,
    float* __restrict__ o, int row0)
{
    if (*flag) ln_body<REMAP, true>(x, sc, bi, o, row0);
    else       ln_body<REMAP, false>(x, sc, bi, o, row0);
}

// ---------------- GEMM: out = A(MxK fp32) @ Bw(KxN dual) + bias ----------------
// MODE 0: -> fp32 ws (qkv), chunk-local rows
// MODE 1: + inverse shift/window row map (global) + residual(x dual) -> d_out dual
// MODE 2: + exact GELU -> fp32 ws (mlp hidden), chunk-local
// MODE 3: + residual(d_out dual, global rows) -> d_out dual
template<int MODE, bool F32>
__device__ void gemm_body(const float* A, const void* Bw, const void* bias,
                          const void* res, void* out, int K, int Ncols, int row0)
{
    __shared__ __align__(16) float As[16][128];  // [k][m]
    __shared__ __align__(16) float Bs[16][64];   // [k][n]
    const int t  = threadIdx.x;
    const int tx = t & 15, ty = t >> 4;
    const int m0 = blockIdx.x * 128;
    const int n0 = blockIdx.y * 64;
    const int am = t >> 1, ak = (t & 1) * 8;
    const int bk = t >> 4, bn = (t & 15) * 4;
    float acc[8][4] = {};

    for (int k0 = 0; k0 < K; k0 += 16) {
        #pragma unroll
        for (int j = 0; j < 8; j++)
            As[ak + j][am] = A[(size_t)(m0 + am) * K + k0 + ak + j];
        #pragma unroll
        for (int j = 0; j < 4; j++)
            Bs[bk][bn + j] = ldg<F32>(Bw, (size_t)(k0 + bk) * Ncols + n0 + bn + j);
        __syncthreads();
        #pragma unroll
        for (int kk = 0; kk < 16; kk++) {
            const float4 a0 = *reinterpret_cast<const float4*>(&As[kk][ty * 8]);
            const float4 a1 = *reinterpret_cast<const float4*>(&As[kk][ty * 8 + 4]);
            const float4 b0 = *reinterpret_cast<const float4*>(&Bs[kk][tx * 4]);
            float ar[8] = {a0.x, a0.y, a0.z, a0.w, a1.x, a1.y, a1.z, a1.w};
            float br[4] = {b0.x, b0.y, b0.z, b0.w};
            #pragma unroll
            for (int a = 0; a < 8; a++)
                #pragma unroll
                for (int b = 0; b < 4; b++)
                    acc[a][b] += ar[a] * br[b];
        }
        __syncthreads();
    }

    float bia[4];
    #pragma unroll
    for (int b = 0; b < 4; b++) bia[b] = ldg<F32>(bias, n0 + tx * 4 + b);

    #pragma unroll
    for (int a = 0; a < 8; a++) {
        const int rl = m0 + ty * 8 + a;      // chunk-local row
        size_t orow;
        if (MODE == 1) {
            int rg = row0 + rl;              // global window-space row
            int w = rg >> 6, n = rg & 63;
            int b_ = w >> 8, wi = (w >> 4) & 15, wj = w & 15;
            int ii = wi * 8 + (n >> 3), jj = wj * 8 + (n & 7);
            int fi = (ii + SHIFT) & 127, fj = (jj + SHIFT) & 127;
            orow = ((size_t)b_ << 14) + ((size_t)fi << 7) + fj;   // global pixel row
        } else if (MODE == 3) {
            orow = (size_t)(row0 + rl);      // global row into d_out
        } else {
            orow = (size_t)rl;               // chunk-local
        }
        size_t o = orow * Ncols + n0 + tx * 4;
        float v[4];
        #pragma unroll
        for (int b = 0; b < 4; b++) v[b] = acc[a][b] + bia[b];
        if (MODE == 1 || MODE == 3) {
            #pragma unroll
            for (int b = 0; b < 4; b++) v[b] += ldg<F32>(res, o + b);
        }
        if (MODE == 2) {
            #pragma unroll
            for (int b = 0; b < 4; b++)
                v[b] = v[b] * 0.5f * (1.0f + erff(v[b] * 0.70710678118654752f));
        }
        if (MODE == 0 || MODE == 2) {
            float* of = (float*)out;
            #pragma unroll
            for (int b = 0; b < 4; b++) of[o + b] = v[b];
        } else {
            #pragma unroll
            for (int b = 0; b < 4; b++) stg<F32>(out, o + b, v[b]);
        }
    }
}

template<int MODE>
__global__ __launch_bounds__(256) void gemm_kernel(
    const int* __restrict__ flag, const float* __restrict__ A,
    const void* __restrict__ Bw, const void* __restrict__ bias,
    const void* __restrict__ res, void* __restrict__ out,
    int K, int Ncols, int row0)
{
    if (*flag) gemm_body<MODE, true>(A, Bw, bias, res, out, K, Ncols, row0);
    else       gemm_body<MODE, false>(A, Bw, bias, res, out, K, Ncols, row0);
}

// ---------------- Windowed attention (all fp32 except rpb) ----------------
template<bool F32>
__device__ void attn_body(const float* qkv, const void* rpb, float* out)
{
    __shared__ __align__(16) float qT[32][64];   // [d][n]
    __shared__ __align__(16) float kT[32][64];   // [d][n]
    __shared__ __align__(16) float vsm[64][32];  // [n][d]
    __shared__ __align__(16) float S[64][68];
    __shared__ float bias_s[225 * 6];
    const int t = threadIdx.x;
    const int w = blockIdx.x / 6;
    const int h = blockIdx.x % 6;

    for (int i = t; i < 1350; i += 256) bias_s[i] = ldg<F32>(rpb, i);
    {
        const int n = t >> 2, d0 = (t & 3) * 8;
        size_t base = (size_t)(w * 64 + n) * C3 + h * 32 + d0;
        #pragma unroll
        for (int i = 0; i < 8; i++) {
            qT[d0 + i][n]  = qkv[base + i];
            kT[d0 + i][n]  = qkv[base + 192 + i];
            vsm[n][d0 + i] = qkv[base + 384 + i];
        }
    }
    __syncthreads();

    {
        const int i0 = (t >> 4) * 4, j0 = (t & 15) * 4;
        float sacc[4][4] = {};
        #pragma unroll
        for (int kk = 0; kk < 32; kk++) {
            float4 q4 = *reinterpret_cast<float4*>(&qT[kk][i0]);
            float4 k4 = *reinterpret_cast<float4*>(&kT[kk][j0]);
            float qa[4] = {q4.x, q4.y, q4.z, q4.w};
            float kb[4] = {k4.x, k4.y, k4.z, k4.w};
            #pragma unroll
            for (int a = 0; a < 4; a++)
                #pragma unroll
                for (int b = 0; b < 4; b++)
                    sacc[a][b] += qa[a] * kb[b];
        }
        #pragma unroll
        for (int a = 0; a < 4; a++) {
            int i = i0 + a;
            #pragma unroll
            for (int b = 0; b < 4; b++) {
                int j = j0 + b;
                int rel = ((i >> 3) - (j >> 3) + 7) * 15 + ((i & 7) - (j & 7) + 7);
                S[i][j] = sacc[a][b] * 0.17677669529663687f + bias_s[rel * 6 + h];
            }
        }
    }
    __syncthreads();

    {
        const int r = t >> 2, q = (t & 3) * 16;
        float mx = -1e30f;
        #pragma unroll
        for (int j = 0; j < 16; j++) mx = fmaxf(mx, S[r][q + j]);
        mx = fmaxf(mx, __shfl_xor(mx, 1));
        mx = fmaxf(mx, __shfl_xor(mx, 2));
        float sm = 0.f;
        #pragma unroll
        for (int j = 0; j < 16; j++) { float e = __expf(S[r][q + j] - mx); S[r][q + j] = e; sm += e; }
        sm += __shfl_xor(sm, 1);
        sm += __shfl_xor(sm, 2);
        float inv = 1.0f / sm;
        #pragma unroll
        for (int j = 0; j < 16; j++) S[r][q + j] *= inv;
    }
    __syncthreads();

    {
        const int oi = (t >> 4) * 4, d0 = (t & 15) * 2;
        float a0 = 0, a1 = 0, a2 = 0, a3 = 0, c0 = 0, c1 = 0, c2 = 0, c3 = 0;
        for (int j = 0; j < 64; j++) {
            float2 vj = *reinterpret_cast<float2*>(&vsm[j][d0]);
            float s0 = S[oi][j], s1 = S[oi + 1][j], s2 = S[oi + 2][j], s3 = S[oi + 3][j];
            a0 += s0 * vj.x; c0 += s0 * vj.y;
            a1 += s1 * vj.x; c1 += s1 * vj.y;
            a2 += s2 * vj.x; c2 += s2 * vj.y;
            a3 += s3 * vj.x; c3 += s3 * vj.y;
        }
        float oa[4] = {a0, a1, a2, a3}, ob[4] = {c0, c1, c2, c3};
        #pragma unroll
        for (int a = 0; a < 4; a++) {
            size_t o = (size_t)(w * 64 + oi + a) * CC + h * 32 + d0;
            out[o]     = oa[a];
            out[o + 1] = ob[a];
        }
    }
}

__global__ __launch_bounds__(256) void attn_kernel(
    const int* __restrict__ flag, const float* __restrict__ qkv,
    const void* __restrict__ rpb, float* __restrict__ out)
{
    if (*flag) attn_body<true>(qkv, rpb, out);
    else       attn_body<false>(qkv, rpb, out);
}

// ---------------- launch ----------------
extern "C" void kernel_launch(void* const* d_in, const int* in_sizes, int n_in,
                              void* d_out, int out_size, void* d_ws, size_t ws_size,
                              hipStream_t stream)
{
    const void* x      = d_in[0];
    const void* qkv_w  = d_in[1];
    const void* qkv_b  = d_in[2];
    const void* proj_w = d_in[3];
    const void* proj_b = d_in[4];
    const void* rpb    = d_in[5];
    const void* n1s    = d_in[6];
    const void* n1b    = d_in[7];
    const void* n2s    = d_in[8];
    const void* n2b    = d_in[9];
    const void* w1     = d_in[10];
    const void* b1     = d_in[11];
    const void* w2     = d_in[12];
    const void* b2     = d_in[13];

    // chunking: per-chunk fp32 intermediates need R*960 floats = R*3840 bytes (+1 KiB flag area)
    int nch = 1;
    while (nch < 128 && ((size_t)(MROWS / nch) * 3840 + 1024) > ws_size) nch *= 2;
    const int R = MROWS / nch;

    int*   flag = (int*)d_ws;
    float* f    = (float*)((char*)d_ws + 1024);
    float* xw   = f;                        // R*192   (phase1)
    float* qkvc = f + (size_t)R * 192;      // R*576   (phase1)
    float* aout = f + (size_t)R * 768;      // R*192   (phase1)
    float* xn   = f;                        // R*192   (phase2)
    float* hbuf = f + (size_t)R * 192;      // R*768   (phase2)

    detect_kernel<<<1, 256, 0, stream>>>(x, flag);

    // phase 1: LN1+shift+window -> qkv -> attn -> proj+unshift+residual(x) -> d_out (x2)
    for (int c = 0; c < nch; c++) {
        const int row0 = c * R;
        ln_kernel<true><<<R, 64, 0, stream>>>(flag, x, n1s, n1b, xw, row0);
        gemm_kernel<0><<<dim3(R / 128, C3 / 64), 256, 0, stream>>>(
            flag, xw, qkv_w, qkv_b, nullptr, qkvc, CC, C3, 0);
        attn_kernel<<<(R / 64) * 6, 256, 0, stream>>>(flag, qkvc, rpb, aout);
        gemm_kernel<1><<<dim3(R / 128, CC / 64), 256, 0, stream>>>(
            flag, aout, proj_w, proj_b, x, d_out, CC, CC, row0);
    }

    // phase 2: LN2 -> mlp1+gelu -> mlp2+residual ; x2 lives in d_out (global rows via row0)
    for (int c = 0; c < nch; c++) {
        const int row0 = c * R;
        ln_kernel<false><<<R, 64, 0, stream>>>(flag, d_out, n2s, n2b, xn, row0);
        gemm_kernel<2><<<dim3(R / 128, CM / 64), 256, 0, stream>>>(
            flag, xn, w1, b1, nullptr, hbuf, CC, CM, 0);
        gemm_kernel<3><<<dim3(R / 128, CC / 64), 256, 0, stream>>>(
            flag, hbuf, w2, b2, d_out, d_out, CM, CC, row0);
    }
}